// Round 16
// baseline (115.726 us; speedup 1.0000x reference)
//
#include <hip/hip_runtime.h>
#include <stdint.h>

// Geometry fixed by the reference: A bits [4,512,512,32], B bits [512,512,32]
#define BATCH 4
#define MDIM  512
#define KDIM  512
#define NDIM  512
#define ROWS  (BATCH * MDIM)   // 2048 flattened output rows
#define BR    8                // C rows per block (8 accs/thread)
#define BCOLS 256              // C cols per block (1 col/thread)
#define KC    32               // k-chunk staged per barrier round
#define NCH   (KDIM / KC)      // 16 chunks

#define WORDS_A (ROWS * KDIM)        // 1,048,576 decoded fp32 words of A
#define WORDS_B (KDIM * NDIM)        //   262,144 decoded fp32 words of B
#define WORDS_T (WORDS_A + WORDS_B)  // 1,310,720
#define DEC_BLOCKS 2048
#define DEC_WAVES  (DEC_BLOCKS * 4)              // 8192 waves
#define DEC_ITERS  (WORDS_T / (32 * DEC_WAVES))  // 5 (exact)

// Native vector types accepted by __builtin_nontemporal_load/store.
typedef unsigned int u32x4 __attribute__((ext_vector_type(4)));
typedef float        f32x4 __attribute__((ext_vector_type(4)));

// Spread 8 bits so bit i lands at position 4*i (exact integer op).
__device__ __forceinline__ uint32_t spread4(uint32_t x) {
    x = (x | (x << 12)) & 0x000F000Fu;
    x = (x | (x << 6))  & 0x03030303u;
    x = (x | (x << 3))  & 0x11111111u;
    return x;
}

// ---------------------------------------------------------------------------
// Decode: pulse bits (float {0,1}, bit0=LSB) -> u32 words, fully coalesced.
// NT loads (stream-once). Static trip count (5), 4 KiB/wave/iter. Bit of v
// is bit29 of its IEEE pattern (1.0f = 0x3F800000). Integer-exact.
// ---------------------------------------------------------------------------
__global__ __launch_bounds__(256) void decode_all(const float* __restrict__ Abits,
                                                  const float* __restrict__ Bbits,
                                                  uint32_t* __restrict__ Au,
                                                  uint32_t* __restrict__ Bu) {
    const int lane = threadIdx.x & 63;
    const int waveId = (blockIdx.x * blockDim.x + threadIdx.x) >> 6;
    const int sh = lane & 56;                 // 8*(lane>>3)

#pragma unroll
    for (int i = 0; i < DEC_ITERS; ++i) {
        const int wb = (waveId + i * DEC_WAVES) * 32;   // 32 words per wave-iter
        const float* src;
        uint32_t* dst;
        if (wb < WORDS_A) { src = Abits + (size_t)wb * 32;             dst = Au + wb; }
        else              { src = Bbits + (size_t)(wb - WORDS_A) * 32; dst = Bu + (wb - WORDS_A); }

        const u32x4* sp = (const u32x4*)src;
        u32x4 v0 = __builtin_nontemporal_load(sp + lane);
        u32x4 v1 = __builtin_nontemporal_load(sp + lane + 64);
        u32x4 v2 = __builtin_nontemporal_load(sp + lane + 128);
        u32x4 v3 = __builtin_nontemporal_load(sp + lane + 192);

        unsigned long long m[16];
        m[0]  = __ballot((v0.x >> 29) & 1u);  m[1]  = __ballot((v0.y >> 29) & 1u);
        m[2]  = __ballot((v0.z >> 29) & 1u);  m[3]  = __ballot((v0.w >> 29) & 1u);
        m[4]  = __ballot((v1.x >> 29) & 1u);  m[5]  = __ballot((v1.y >> 29) & 1u);
        m[6]  = __ballot((v1.z >> 29) & 1u);  m[7]  = __ballot((v1.w >> 29) & 1u);
        m[8]  = __ballot((v2.x >> 29) & 1u);  m[9]  = __ballot((v2.y >> 29) & 1u);
        m[10] = __ballot((v2.z >> 29) & 1u);  m[11] = __ballot((v2.w >> 29) & 1u);
        m[12] = __ballot((v3.x >> 29) & 1u);  m[13] = __ballot((v3.y >> 29) & 1u);
        m[14] = __ballot((v3.z >> 29) & 1u);  m[15] = __ballot((v3.w >> 29) & 1u);

        if ((lane & 7) == 0) {
#pragma unroll
            for (int g = 0; g < 4; ++g) {
                uint32_t w = (spread4((uint32_t)(m[4*g+0] >> sh) & 0xFFu) << 0)
                           | (spread4((uint32_t)(m[4*g+1] >> sh) & 0xFFu) << 1)
                           | (spread4((uint32_t)(m[4*g+2] >> sh) & 0xFFu) << 2)
                           | (spread4((uint32_t)(m[4*g+3] >> sh) & 0xFFu) << 3);
                dst[8 * g + (lane >> 3)] = w;    // cached: consumed by gemm
            }
        }
    }
}

// ---------------------------------------------------------------------------
// GEMM (exact np.einsum semantics: per output element, single accumulator,
// k ascending, one FMA per step) + LDS-transposed NT bit-encode epilogue.
// Block: 8 rows x 256 cols, 256 threads; thread = 1 col, 8 row-accs.
// B staged per KC=32 chunk via ASYNC global_load_lds (32 KB, double-buffered
// 64 KB -> 2 blocks/CU), prefetched one chunk ahead. Per k: ONE conflict-free
// ds_read_b32 feeds EIGHT FMAs (halves the binding LDS-issue cost vs BR=4);
// acc-chain ILP of 8 covers FMA latency at 2 waves/SIMD. A loads are
// wave-uniform (scalar path). B L2 traffic: 256 MB.
// ---------------------------------------------------------------------------
__global__ __launch_bounds__(256) void gemm_encode(const float* __restrict__ A,
                                                   const float* __restrict__ B,
                                                   float* __restrict__ outbits) {
    __shared__ __align__(16) float Bs[2][KC][BCOLS];   // 64 KiB double buffer

    const int tid = threadIdx.x;
    const int rowBase = blockIdx.x * BR;
    const int n0 = blockIdx.y * BCOLS;

    float acc[BR];
#pragma unroll
    for (int r = 0; r < BR; ++r) acc[r] = 0.0f;

    const float* Arow = A + (size_t)rowBase * KDIM;

    // Async stage of k-chunk c into buffer buf: 32 KB, linear lane->LDS.
    auto stage = [&](int buf, int c) {
#pragma unroll
        for (int it = 0; it < (KC * BCOLS) / (256 * 4); ++it) {   // 8 iters
            int ci = it * 1024 + tid * 4;     // float index within chunk
            int kk = ci >> 8;                 // /BCOLS
            int j  = ci & (BCOLS - 1);
            const float* gsrc = B + (size_t)(c * KC + kk) * NDIM + n0 + j;
            __builtin_amdgcn_global_load_lds(
                (const __attribute__((address_space(1))) void*)gsrc,
                (__attribute__((address_space(3))) void*)(&Bs[buf][0][0] + ci),
                16, 0, 0);
        }
    };

    stage(0, 0);
    __syncthreads();                  // buffer 0 landed

    for (int c = 0; c < NCH; ++c) {
        if (c + 1 < NCH) stage((c + 1) & 1, c + 1);   // async prefetch

        const int cur = c & 1;
#pragma unroll
        for (int g8 = 0; g8 < KC / 8; ++g8) {         // four 8-k groups
            const int k0 = c * KC + g8 * 8;
            float bc[8];
#pragma unroll
            for (int i = 0; i < 8; ++i) bc[i] = Bs[cur][g8 * 8 + i][tid];

            float4 a0[BR], a1[BR];
#pragma unroll
            for (int r = 0; r < BR; ++r) {
                a0[r] = *(const float4*)(Arow + (size_t)r * KDIM + k0);
                a1[r] = *(const float4*)(Arow + (size_t)r * KDIM + k0 + 4);
            }
            // k ascending per element; one FMA per step.
#pragma unroll
            for (int r = 0; r < BR; ++r) {
                acc[r] = __builtin_fmaf(a0[r].x, bc[0], acc[r]);
                acc[r] = __builtin_fmaf(a0[r].y, bc[1], acc[r]);
                acc[r] = __builtin_fmaf(a0[r].z, bc[2], acc[r]);
                acc[r] = __builtin_fmaf(a0[r].w, bc[3], acc[r]);
                acc[r] = __builtin_fmaf(a1[r].x, bc[4], acc[r]);
                acc[r] = __builtin_fmaf(a1[r].y, bc[5], acc[r]);
                acc[r] = __builtin_fmaf(a1[r].z, bc[6], acc[r]);
                acc[r] = __builtin_fmaf(a1[r].w, bc[7], acc[r]);
            }
        }
        __syncthreads();   // drains vmcnt (next buffer landed) + read fence
    }

    // ---- epilogue: transpose through LDS (alias Bs[0]), NT bit stores ----
    uint32_t* Us = (uint32_t*)&Bs[0][0][0];   // [BR][BCOLS]
#pragma unroll
    for (int r = 0; r < BR; ++r) Us[r * BCOLS + tid] = __float_as_uint(acc[r]);
    __syncthreads();

    float* oBase = outbits + ((size_t)rowBase * NDIM + n0) * 32;
    const int b = (tid & 7) * 4;
#pragma unroll
    for (int r = 0; r < BR; ++r) {
        float* o = oBase + (size_t)r * NDIM * 32;
#pragma unroll
        for (int it = 0; it < 8; ++it) {
            uint32_t u = Us[r * BCOLS + it * 32 + (tid >> 3)];   // 8-lane broadcast
            f32x4 q;
            q.x = (float)((u >> (b + 0)) & 1u);
            q.y = (float)((u >> (b + 1)) & 1u);
            q.z = (float)((u >> (b + 2)) & 1u);
            q.w = (float)((u >> (b + 3)) & 1u);
            __builtin_nontemporal_store(q, (f32x4*)(o + it * 1024 + tid * 4));
        }
    }
}

extern "C" void kernel_launch(void* const* d_in, const int* in_sizes, int n_in,
                              void* d_out, int out_size, void* d_ws, size_t ws_size,
                              hipStream_t stream) {
    const float* Abits = (const float*)d_in[0];   // [4,512,512,32] floats {0,1}
    const float* Bbits = (const float*)d_in[1];   // [512,512,32]
    float* out = (float*)d_out;                   // [4,512,512,32]

    // Workspace: A_u32 (4 MiB) | B_u32 (1 MiB)
    uint32_t* A_u = (uint32_t*)d_ws;
    uint32_t* B_u = A_u + WORDS_A;

    decode_all<<<DEC_BLOCKS, 256, 0, stream>>>(Abits, Bbits, A_u, B_u);

    dim3 grid(ROWS / BR, NDIM / BCOLS);           // (256, 2) = 512 blocks
    gemm_encode<<<grid, 256, 0, stream>>>((const float*)A_u, (const float*)B_u, out);
}

// Round 17
// 78.297 us; speedup vs baseline: 1.4780x; 1.4780x over previous
//
#include <hip/hip_runtime.h>
#include <stdint.h>

// Geometry fixed by the reference: A bits [4,512,512,32], B bits [512,512,32]
#define BATCH 4
#define MDIM  512
#define KDIM  512
#define NDIM  512
#define ROWS  (BATCH * MDIM)   // 2048 flattened output rows
#define BR    4                // C rows per block (4 accs/thread)
#define BCOLS 256              // C cols per block (1 col/thread)
#define KC    16               // k-chunk staged per barrier round
#define NCH   (KDIM / KC)      // 32 chunks

#define WORDS_A (ROWS * KDIM)        // 1,048,576 decoded fp32 words of A
#define WORDS_B (KDIM * NDIM)        //   262,144 decoded fp32 words of B
#define WORDS_T (WORDS_A + WORDS_B)  // 1,310,720
#define DEC_BLOCKS 2048
#define DEC_WAVES  (DEC_BLOCKS * 4)              // 8192 waves
#define DEC_ITERS  (WORDS_T / (32 * DEC_WAVES))  // 5 (exact)

// Native vector types accepted by __builtin_nontemporal_load/store.
typedef unsigned int u32x4 __attribute__((ext_vector_type(4)));
typedef float        f32x4 __attribute__((ext_vector_type(4)));

// Spread 8 bits so bit i lands at position 4*i (exact integer op).
__device__ __forceinline__ uint32_t spread4(uint32_t x) {
    x = (x | (x << 12)) & 0x000F000Fu;
    x = (x | (x << 6))  & 0x03030303u;
    x = (x | (x << 3))  & 0x11111111u;
    return x;
}

// ---------------------------------------------------------------------------
// Decode: pulse bits (float {0,1}, bit0=LSB) -> u32 words, fully coalesced.
// NT loads (stream-once). Static trip count (5), 4 KiB/wave/iter. Bit of v
// is bit29 of its IEEE pattern (1.0f = 0x3F800000). Integer-exact.
// Measured ~29 us on 177 MB = ~6.1 TB/s (~97% of achievable copy BW).
// ---------------------------------------------------------------------------
__global__ __launch_bounds__(256) void decode_all(const float* __restrict__ Abits,
                                                  const float* __restrict__ Bbits,
                                                  uint32_t* __restrict__ Au,
                                                  uint32_t* __restrict__ Bu) {
    const int lane = threadIdx.x & 63;
    const int waveId = (blockIdx.x * blockDim.x + threadIdx.x) >> 6;
    const int sh = lane & 56;                 // 8*(lane>>3)

#pragma unroll
    for (int i = 0; i < DEC_ITERS; ++i) {
        const int wb = (waveId + i * DEC_WAVES) * 32;   // 32 words per wave-iter
        const float* src;
        uint32_t* dst;
        if (wb < WORDS_A) { src = Abits + (size_t)wb * 32;             dst = Au + wb; }
        else              { src = Bbits + (size_t)(wb - WORDS_A) * 32; dst = Bu + (wb - WORDS_A); }

        const u32x4* sp = (const u32x4*)src;
        u32x4 v0 = __builtin_nontemporal_load(sp + lane);
        u32x4 v1 = __builtin_nontemporal_load(sp + lane + 64);
        u32x4 v2 = __builtin_nontemporal_load(sp + lane + 128);
        u32x4 v3 = __builtin_nontemporal_load(sp + lane + 192);

        unsigned long long m[16];
        m[0]  = __ballot((v0.x >> 29) & 1u);  m[1]  = __ballot((v0.y >> 29) & 1u);
        m[2]  = __ballot((v0.z >> 29) & 1u);  m[3]  = __ballot((v0.w >> 29) & 1u);
        m[4]  = __ballot((v1.x >> 29) & 1u);  m[5]  = __ballot((v1.y >> 29) & 1u);
        m[6]  = __ballot((v1.z >> 29) & 1u);  m[7]  = __ballot((v1.w >> 29) & 1u);
        m[8]  = __ballot((v2.x >> 29) & 1u);  m[9]  = __ballot((v2.y >> 29) & 1u);
        m[10] = __ballot((v2.z >> 29) & 1u);  m[11] = __ballot((v2.w >> 29) & 1u);
        m[12] = __ballot((v3.x >> 29) & 1u);  m[13] = __ballot((v3.y >> 29) & 1u);
        m[14] = __ballot((v3.z >> 29) & 1u);  m[15] = __ballot((v3.w >> 29) & 1u);

        if ((lane & 7) == 0) {
#pragma unroll
            for (int g = 0; g < 4; ++g) {
                uint32_t w = (spread4((uint32_t)(m[4*g+0] >> sh) & 0xFFu) << 0)
                           | (spread4((uint32_t)(m[4*g+1] >> sh) & 0xFFu) << 1)
                           | (spread4((uint32_t)(m[4*g+2] >> sh) & 0xFFu) << 2)
                           | (spread4((uint32_t)(m[4*g+3] >> sh) & 0xFFu) << 3);
                dst[8 * g + (lane >> 3)] = w;    // cached: consumed by gemm
            }
        }
    }
}

// ---------------------------------------------------------------------------
// GEMM (exact np.einsum semantics: per output element, single accumulator,
// k ascending, one FMA per step) + LDS-transposed NT bit-encode epilogue.
// Block: 4 rows x 256 cols, 256 threads; thread = 1 col, 4 row-accs.
// B staged per KC=16 chunk via ASYNC global_load_lds (double-buffered 32 KB),
// prefetched one chunk ahead; per k ONE conflict-free ds_read_b32 + 4 FMAs.
// A loads wave-uniform (scalar path). 1024 blocks = 4 blocks/CU = 16 waves/CU
// (the measured occupancy floor for this kernel family).
// ---------------------------------------------------------------------------
__global__ __launch_bounds__(256) void gemm_encode(const float* __restrict__ A,
                                                   const float* __restrict__ B,
                                                   float* __restrict__ outbits) {
    __shared__ __align__(16) float Bs[2][KC][BCOLS];   // 32 KiB double buffer

    const int tid = threadIdx.x;
    const int rowBase = blockIdx.x * BR;
    const int n0 = blockIdx.y * BCOLS;

    float acc[BR];
#pragma unroll
    for (int r = 0; r < BR; ++r) acc[r] = 0.0f;

    const float* Arow = A + (size_t)rowBase * KDIM;

    // Async stage of k-chunk c into buffer buf: 16 KB, linear lane->LDS.
    auto stage = [&](int buf, int c) {
#pragma unroll
        for (int it = 0; it < (KC * BCOLS) / (256 * 4); ++it) {   // 4 iters
            int ci = it * 1024 + tid * 4;     // float index within chunk
            int kk = ci >> 8;                 // /BCOLS
            int j  = ci & (BCOLS - 1);
            const float* gsrc = B + (size_t)(c * KC + kk) * NDIM + n0 + j;
            __builtin_amdgcn_global_load_lds(
                (const __attribute__((address_space(1))) void*)gsrc,
                (__attribute__((address_space(3))) void*)(&Bs[buf][0][0] + ci),
                16, 0, 0);
        }
    };

    stage(0, 0);
    __syncthreads();                  // buffer 0 landed

    for (int c = 0; c < NCH; ++c) {
        if (c + 1 < NCH) stage((c + 1) & 1, c + 1);   // async prefetch

        const int cur = c & 1;
#pragma unroll
        for (int g8 = 0; g8 < KC / 8; ++g8) {         // two 8-k groups
            const int k0 = c * KC + g8 * 8;
            float bc[8];
#pragma unroll
            for (int i = 0; i < 8; ++i) bc[i] = Bs[cur][g8 * 8 + i][tid];

            float4 a0[BR], a1[BR];
#pragma unroll
            for (int r = 0; r < BR; ++r) {
                a0[r] = *(const float4*)(Arow + (size_t)r * KDIM + k0);
                a1[r] = *(const float4*)(Arow + (size_t)r * KDIM + k0 + 4);
            }
            // k ascending per element; one FMA per step.
#pragma unroll
            for (int r = 0; r < BR; ++r) {
                acc[r] = __builtin_fmaf(a0[r].x, bc[0], acc[r]);
                acc[r] = __builtin_fmaf(a0[r].y, bc[1], acc[r]);
                acc[r] = __builtin_fmaf(a0[r].z, bc[2], acc[r]);
                acc[r] = __builtin_fmaf(a0[r].w, bc[3], acc[r]);
                acc[r] = __builtin_fmaf(a1[r].x, bc[4], acc[r]);
                acc[r] = __builtin_fmaf(a1[r].y, bc[5], acc[r]);
                acc[r] = __builtin_fmaf(a1[r].z, bc[6], acc[r]);
                acc[r] = __builtin_fmaf(a1[r].w, bc[7], acc[r]);
            }
        }
        __syncthreads();   // drains vmcnt (next buffer landed) + read fence
    }

    // ---- epilogue: transpose through LDS (alias Bs[0]), NT bit stores ----
    uint32_t* Us = (uint32_t*)&Bs[0][0][0];   // [BR][BCOLS]
#pragma unroll
    for (int r = 0; r < BR; ++r) Us[r * BCOLS + tid] = __float_as_uint(acc[r]);
    __syncthreads();

    float* oBase = outbits + ((size_t)rowBase * NDIM + n0) * 32;
    const int b = (tid & 7) * 4;
#pragma unroll
    for (int r = 0; r < BR; ++r) {
        float* o = oBase + (size_t)r * NDIM * 32;
#pragma unroll
        for (int it = 0; it < 8; ++it) {
            uint32_t u = Us[r * BCOLS + it * 32 + (tid >> 3)];   // 8-lane broadcast
            f32x4 q;
            q.x = (float)((u >> (b + 0)) & 1u);
            q.y = (float)((u >> (b + 1)) & 1u);
            q.z = (float)((u >> (b + 2)) & 1u);
            q.w = (float)((u >> (b + 3)) & 1u);
            __builtin_nontemporal_store(q, (f32x4*)(o + it * 1024 + tid * 4));
        }
    }
}

extern "C" void kernel_launch(void* const* d_in, const int* in_sizes, int n_in,
                              void* d_out, int out_size, void* d_ws, size_t ws_size,
                              hipStream_t stream) {
    const float* Abits = (const float*)d_in[0];   // [4,512,512,32] floats {0,1}
    const float* Bbits = (const float*)d_in[1];   // [512,512,32]
    float* out = (float*)d_out;                   // [4,512,512,32]

    // Workspace: A_u32 (4 MiB) | B_u32 (1 MiB)
    uint32_t* A_u = (uint32_t*)d_ws;
    uint32_t* B_u = A_u + WORDS_A;

    decode_all<<<DEC_BLOCKS, 256, 0, stream>>>(Abits, Bbits, A_u, B_u);

    dim3 grid(ROWS / BR, NDIM / BCOLS);           // (512, 2) = 1024 blocks
    gemm_encode<<<grid, 256, 0, stream>>>((const float*)A_u, (const float*)B_u, out);
}